// Round 5
// baseline (888.810 us; speedup 1.0000x reference)
//
#include <hip/hip_runtime.h>

#define NORI 8
#define KS 7
#define CH 32
#define IMG 224
#define STRIP 16           // output rows per block
#define SROWS (STRIP + 6)  // staged input rows (halo 3 top+bottom) = 22
#define PITCH 232          // floats per staged row; col j holds x-col (j-4)

typedef float f4 __attribute__((ext_vector_type(4)));

// read the 12-float window of staged row `rowidx` for lane `l` (3x ds_read_b128)
#define READ_WIN(dst, rowidx) do {                                         \
    const f4* p_ = (const f4*)&s_in[(rowidx) * PITCH + 4 * l];             \
    f4 u0 = p_[0], u1 = p_[1], u2 = p_[2];                                 \
    dst[0]=u0.x; dst[1]=u0.y; dst[2]=u0.z;  dst[3]=u0.w;                   \
    dst[4]=u1.x; dst[5]=u1.y; dst[6]=u1.z;  dst[7]=u1.w;                   \
    dst[8]=u2.x; dst[9]=u2.y; dst[10]=u2.z; dst[11]=u2.w; } while (0)

__global__ __launch_bounds__(256, 4)   // cap 128 VGPR -> no spills (round-3 lesson)
void gabor_dw_conv(const float* __restrict__ x, const float* __restrict__ filt,
                   float* __restrict__ out) {
    __shared__ __align__(16) float s_in[SROWS * PITCH];   // 20416 B

    // grid = 14 strips * 512 planes * 2 ori-halves = 14336 = 8 * 1792 (bijective swizzle)
    const int cpx = (14 * CH * 16 * 2) / 8;      // 1792
    const int bid = blockIdx.x;
    const int logical = (bid & 7) * cpx + (bid >> 3);
    const int strip = logical % 14;
    const int t     = logical / 14;              // 0..1023
    const int half  = t & 1;                     // two halves of same plane adjacent in time
    const int plane = t >> 1;                    // 0..511
    const int c = plane & (CH - 1);
    const int b = plane >> 5;
    const int gy0 = strip * STRIP;

    const int tid = threadIdx.x;
    const int wv  = tid >> 6;                    // wave 0..3
    const int l   = tid & 63;
    const int ori = half * 4 + wv;               // this wave's orientation

    // ---- stage input strip rows gy0-3 .. gy0+18 (coalesced 896B/row) ----
    const float* xp = x + (size_t)(b * CH + c) * (IMG * IMG);
    {
        const int gxw = l - 1;                   // float4 index in global row
        const bool xok = (gxw >= 0) && (gxw < IMG / 4);
        for (int row = wv; row < SROWS; row += 4) {
            int gy = gy0 - 3 + row;
            f4 v = (f4)0.f;
            if (xok && gy >= 0 && gy < IMG) v = *(const f4*)(xp + gy * IMG + 4 * gxw);
            if (l < 58) *(f4*)&s_in[row * PITCH + 4 * l] = v;
        }
    }

    // ---- hoist this wave's 49 weights into VGPRs ----
    const float* fw = filt + ((size_t)c * NORI + ori) * 49;
    float w[49];
    #pragma unroll
    for (int k = 0; k < 49; ++k) w[k] = fw[k];

    __syncthreads();
    if (l >= 56) return;                         // 56 lanes x 4 px = 224

    const int x0 = 4 * l;
    float* op = out + ((size_t)(b * (CH * NORI) + c * NORI + ori) * IMG + gy0) * IMG + x0;

    // ---- single sweep over the 22 input rows; 7-slot ring of output accumulators ----
    float acc[7][4] = {{0,0,0,0},{0,0,0,0},{0,0,0,0},{0,0,0,0},{0,0,0,0},{0,0,0,0},{0,0,0,0}};

    #pragma unroll
    for (int i = 0; i < SROWS; ++i) {            // input row i -> out rows i-6 .. i
        float W[12];
        READ_WIN(W, i);                          // each input row read from LDS exactly once
        #pragma unroll
        for (int ky = 0; ky < KS; ++ky) {
            const int j = i - ky;                // output row receiving tap ky from row i
            if (j < 0 || j > STRIP - 1) continue;   // folds at compile time (full unroll)
            const int s = j % 7;                 // static ring slot
            #pragma unroll
            for (int kx = 0; kx < KS; ++kx) {
                const float cw = w[ky * 7 + kx];
                #pragma unroll
                for (int p = 0; p < 4; ++p)
                    acc[s][p] += W[p + kx + 1] * cw;   // window idx 1..10
            }
        }
        if (i >= 6) {                            // out row j = i-6 complete: store + recycle
            const int j = i - 6;
            const int s = j % 7;
            f4 v; v.x = acc[s][0]; v.y = acc[s][1]; v.z = acc[s][2]; v.w = acc[s][3];
            __builtin_nontemporal_store(v, (f4*)(op + (size_t)j * IMG));
            acc[s][0] = 0.f; acc[s][1] = 0.f; acc[s][2] = 0.f; acc[s][3] = 0.f;
        }
    }
}

extern "C" void kernel_launch(void* const* d_in, const int* in_sizes, int n_in,
                              void* d_out, int out_size, void* d_ws, size_t ws_size,
                              hipStream_t stream) {
    const float* x = (const float*)d_in[0];
    const float* filt = (const float*)d_in[1];
    float* out = (float*)d_out;

    dim3 grid(14 * CH * 16 * 2);   // strips * channels * batch * ori-halves = 14336
    dim3 block(256);               // 4 waves = 4 orientations per block
    gabor_dw_conv<<<grid, block, 0, stream>>>(x, filt, out);
}